// Round 10
// baseline (599.369 us; speedup 1.0000x reference)
//
#include <hip/hip_runtime.h>
#include <hip/hip_cooperative_groups.h>

namespace cg = cooperative_groups;

typedef _Float16 half4 __attribute__((ext_vector_type(4)));
typedef _Float16 half8 __attribute__((ext_vector_type(8)));
typedef float f32x4 __attribute__((ext_vector_type(4)));

#define NNODE 8192
#define NHID  256
#define RCAP  128
#define KCAP  64
#define GLS   72    // gemm lds row stride (fp16): 144B = 9 quads, conflict-free
#define SK    136   // medoid lds row stride (fp16): 272B = 17 quads, conflict-free

struct SmemGemm   { _Float16 sA[64][GLS]; _Float16 sB[64][GLS]; };
struct SmemDedup  { int lc[2][RCAP]; float lw[2][RCAP]; unsigned char kp[2][RCAP];
                    int s_cw[2][2]; float s_rw[2][2]; };
struct SmemMedoid { _Float16 sh[64][SK]; float s_a[64]; float s_sq[64];
                    float s_cpart[2][64]; float s_u[64]; int s_cols[64];
                    float s_red[4][288]; };   // 23552 B = stage max

// ---------------------------------------------------------------- GEMM tile body
__device__ __forceinline__ void gemm_body(
    char* smraw, const _Float16* __restrict__ Ahi, const _Float16* __restrict__ BT,
    _Float16* __restrict__ Chi, int K, int bm, int bn) {
    SmemGemm& sm = *(SmemGemm*)smraw;
    const int t = threadIdx.x;
    const int lane = t & 63, L15 = lane & 15, q = lane >> 4;
    const int w = t >> 6, wr = w >> 1, wc = w & 1;
    f32x4 acc[2][2];
#pragma unroll
    for (int a = 0; a < 2; ++a)
#pragma unroll
        for (int b2 = 0; b2 < 2; ++b2) acc[a][b2] = (f32x4){0.f, 0.f, 0.f, 0.f};

    for (int k0 = 0; k0 < K; k0 += 64) {
#pragma unroll
        for (int i = 0; i < 2; ++i) {
            int row = i * 32 + (t >> 3), ch = t & 7;
            *(half8*)&sm.sA[row][ch * 8] =
                *(const half8*)(Ahi + (size_t)(bm + row) * K + k0 + ch * 8);
            *(half8*)&sm.sB[row][ch * 8] =
                *(const half8*)(BT + (size_t)(bn + row) * K + k0 + ch * 8);
        }
        __syncthreads();
#pragma unroll
        for (int ks = 0; ks < 2; ++ks) {
            const int ko = ks * 32 + q * 8;
            half8 ah[2], bh[2];
#pragma unroll
            for (int tr = 0; tr < 2; ++tr)
                ah[tr] = *(const half8*)&sm.sA[32 * wr + 16 * tr + L15][ko];
#pragma unroll
            for (int tc = 0; tc < 2; ++tc)
                bh[tc] = *(const half8*)&sm.sB[32 * wc + 16 * tc + L15][ko];
#pragma unroll
            for (int tr = 0; tr < 2; ++tr)
#pragma unroll
                for (int tc = 0; tc < 2; ++tc)
                    acc[tr][tc] = __builtin_amdgcn_mfma_f32_16x16x32_f16(ah[tr], bh[tc], acc[tr][tc], 0, 0, 0);
        }
        __syncthreads();
    }
#pragma unroll
    for (int tr = 0; tr < 2; ++tr)
#pragma unroll
        for (int tc = 0; tc < 2; ++tc)
#pragma unroll
            for (int r = 0; r < 4; ++r) {
                int rowg = bm + 32 * wr + 16 * tr + q * 4 + r;
                int colg = bn + 32 * wc + 16 * tc + L15;
                Chi[(size_t)rowg * NHID + colg] = (_Float16)acc[tr][tc][r];
            }
}

// ---------------------------------------------------------------- dedup body (2 rows per call)
__device__ __forceinline__ void dedup_body(
    char* smraw, const int* __restrict__ nbr, const int* __restrict__ rowcnt,
    const int* __restrict__ deg, int* __restrict__ cols, float* __restrict__ wout,
    float* __restrict__ rsum, int grp) {
    SmemDedup& sm = *(SmemDedup*)smraw;
    const int t = threadIdx.x;
    const int half = t >> 7, st = t & 127;
    const int wid = st >> 6, lane = t & 63;
    const int r = grp * 2 + half;
    int n = rowcnt[r]; if (n > RCAP) n = RCAP;
    if (st < n) sm.lc[half][st] = nbr[r * RCAP + st];
    __syncthreads();
    float dr = 1.f / sqrtf((float)deg[r]);
    bool keep = false; float wv = 0.f;
    if (st < n) {
        int c = sm.lc[half][st];
        int mult = 0; bool first = true;
        for (int i = 0; i < n; ++i) {
            int ci = sm.lc[half][i];
            if (ci == c) { mult++; if (i < st) first = false; }
        }
        keep = first;
        if (first) wv = (float)mult * dr * (1.f / sqrtf((float)deg[c]));
    }
    sm.kp[half][st] = keep ? 1 : 0; sm.lw[half][st] = wv;
    float rv = wv;
#pragma unroll
    for (int d = 1; d < 64; d <<= 1) rv += __shfl_xor(rv, d, 64);
    unsigned long long b = __ballot(keep);
    int pre = __popcll(b & ((1ull << lane) - 1ull));
    int cw = __popcll(b);
    if (lane == 0) { sm.s_cw[half][wid] = cw; sm.s_rw[half][wid] = rv; }
    __syncthreads();
    int total = sm.s_cw[half][0] + sm.s_cw[half][1];
    if (st == 0) rsum[r] = sm.s_rw[half][0] + sm.s_rw[half][1];
    const int base = r * KCAP;
    if (total <= KCAP) {
        int off = (wid ? sm.s_cw[half][0] : 0) + pre;
        if (keep) { cols[base + off] = sm.lc[half][st]; wout[base + off] = wv; }
        for (int m = total + st; m < KCAP; m += 128) { cols[base + m] = r; wout[base + m] = 0.f; }
    } else if (st == 0) {
        for (int s = 0; s < KCAP; ++s) {
            int best = -1;
            for (int i = 0; i < n; ++i) {
                if (!sm.kp[half][i]) continue;
                if (best < 0 || sm.lw[half][i] > sm.lw[half][best] ||
                    (sm.lw[half][i] == sm.lw[half][best] && sm.lc[half][i] < sm.lc[half][best])) best = i;
            }
            cols[base + s] = sm.lc[half][best]; wout[base + s] = sm.lw[half][best]; sm.kp[half][best] = 0;
        }
    }
    __syncthreads();
}

// ---------------------------------------------------------------- medoid body (1 node per call)
__device__ __forceinline__ void medoid_body(
    char* smraw, const _Float16* __restrict__ Xhi, const float* __restrict__ bias,
    float* __restrict__ OutF, _Float16* __restrict__ OutHi,
    const int* __restrict__ cols, const float* __restrict__ wts,
    const float* __restrict__ rsum, int node, int writeH) {
    SmemMedoid& sm = *(SmemMedoid*)smraw;
    const int t = threadIdx.x;
    const int w = t >> 6, lane = t & 63;
    const int L15 = lane & 15, q = lane >> 4;
    const int wr = w >> 1, wc = w & 1;

    if (t < 64) { sm.s_cols[t] = cols[node * KCAP + t]; sm.s_a[t] = wts[node * KCAP + t]; }
    __syncthreads();

    f32x4 acc[2][2];
#pragma unroll
    for (int a = 0; a < 2; ++a)
#pragma unroll
        for (int b = 0; b < 2; ++b) acc[a][b] = (f32x4){0.f, 0.f, 0.f, 0.f};

    const int ch = t & 15, rr = t >> 4;
    for (int phase = 0; phase < 2; ++phase) {
#pragma unroll
        for (int i = 0; i < 4; ++i) {
            int l = i * 16 + rr;
            *(half8*)&sm.sh[l][ch * 8] =
                *(const half8*)(Xhi + ((size_t)sm.s_cols[l] << 8) + phase * 128 + ch * 8);
        }
        __syncthreads();
#pragma unroll
        for (int ks = 0; ks < 4; ++ks) {
            const int ko = ks * 32 + q * 8;
            half8 ah[2], bh[2];
#pragma unroll
            for (int tr = 0; tr < 2; ++tr) ah[tr] = *(const half8*)&sm.sh[32 * wr + 16 * tr + L15][ko];
#pragma unroll
            for (int tc = 0; tc < 2; ++tc) bh[tc] = *(const half8*)&sm.sh[32 * wc + 16 * tc + L15][ko];
#pragma unroll
            for (int tr = 0; tr < 2; ++tr)
#pragma unroll
                for (int tc = 0; tc < 2; ++tc)
                    acc[tr][tc] = __builtin_amdgcn_mfma_f32_16x16x32_f16(ah[tr], bh[tc], acc[tr][tc], 0, 0, 0);
        }
        if (phase == 0) __syncthreads();
    }
    // sm.sh holds dims 128..255 for the epilogue

#pragma unroll
    for (int tr = 0; tr < 2; ++tr)
#pragma unroll
        for (int tc = 0; tc < 2; ++tc)
            if (32 * wr + 16 * tr == 32 * wc + 16 * tc) {
#pragma unroll
                for (int r = 0; r < 4; ++r)
                    if (L15 == q * 4 + r) sm.s_sq[32 * wr + 16 * tr + L15] = acc[tr][tc][r];
            }
    __syncthreads();

    f32x4 sq4[2], a4[2];
#pragma unroll
    for (int tr = 0; tr < 2; ++tr) {
        sq4[tr] = *(const f32x4*)&sm.s_sq[32 * wr + 16 * tr + 4 * q];
        a4[tr]  = *(const f32x4*)&sm.s_a [32 * wr + 16 * tr + 4 * q];
    }
#pragma unroll
    for (int tc = 0; tc < 2; ++tc) {
        const int colg = 32 * wc + 16 * tc + L15;
        const float sqc = sm.s_sq[colg];
        float pj = 0.f;
#pragma unroll
        for (int tr = 0; tr < 2; ++tr)
#pragma unroll
            for (int r = 0; r < 4; ++r) {
                float d2 = sq4[tr][r] + sqc - 2.f * acc[tr][tc][r];
                float dist = d2 > 0.f ? __builtin_amdgcn_sqrtf(d2) : 0.f;
                pj = fmaf(a4[tr][r], dist, pj);
            }
        pj += __shfl_xor(pj, 16, 64);
        pj += __shfl_xor(pj, 32, 64);
        if (q == 0) sm.s_cpart[wr][colg] = pj;
    }
    __syncthreads();

    if (w == 0) {
        int j = lane;
        float c = sm.s_cpart[0][j] + sm.s_cpart[1][j];
        float aj = sm.s_a[j];
        bool valid = aj > 0.f;
        float cv = valid ? c : 3.4e38f;
        float mn = cv;
#pragma unroll
        for (int d = 1; d < 64; d <<= 1) mn = fminf(mn, __shfl_xor(mn, d, 64));
        float e = valid ? __expf(mn - c) * aj : 0.f;
        float s = e;
#pragma unroll
        for (int d = 1; d < 64; d <<= 1) s += __shfl_xor(s, d, 64);
        sm.s_u[j] = e * (rsum[node] / s);
    }
    __syncthreads();

    const int oct = t & 31, jb = t >> 5;
    float accd[8] = {0.f, 0.f, 0.f, 0.f, 0.f, 0.f, 0.f, 0.f};
#pragma unroll
    for (int jj = 0; jj < 8; ++jj) {
        int j = jb * 8 + jj;
        float u = sm.s_u[j];
        half8 xv;
        if (oct < 16) xv = *(const half8*)(Xhi + ((size_t)sm.s_cols[j] << 8) + oct * 8);
        else          xv = *(const half8*)&sm.sh[j][(oct - 16) * 8];
#pragma unroll
        for (int e = 0; e < 8; ++e) accd[e] = fmaf(u, (float)xv[e], accd[e]);
    }
#pragma unroll
    for (int e = 0; e < 8; ++e) accd[e] += __shfl_xor(accd[e], 32, 64);
    if (lane < 32) {
#pragma unroll
        for (int e = 0; e < 8; ++e) sm.s_red[w][9 * oct + e] = accd[e];
    }
    __syncthreads();
    const int idx = 9 * (t >> 3) + (t & 7);
    float o = sm.s_red[0][idx] + sm.s_red[1][idx] + sm.s_red[2][idx] + sm.s_red[3][idx];
    float res = fmaxf(o + bias[t], 0.f);
    size_t oi = (size_t)node * NHID + t;
    if (writeH) OutHi[oi] = (_Float16)res;
    else        OutF[oi] = res;
}

// ---------------------------------------------------------------- prep stage (grid-stride)
__device__ __forceinline__ void stage_prep(
    int gid, int nthr, int bid, int t,
    int* deg, int* rowcnt, int* flag, const void* edges,
    const float* __restrict__ x, _Float16* __restrict__ xh,
    const float* __restrict__ W1, _Float16* __restrict__ w1T,
    const float* __restrict__ W2, _Float16* __restrict__ w2T) {
    for (int i = gid; i < NNODE; i += nthr) { deg[i] = 0; rowcnt[i] = 0; }
    if (bid == 0 && t < 64) {
        const long long* e = (const long long*)edges;
        long long v = e[t];
        unsigned long long bad = __ballot(v < 0 || v >= (long long)NNODE);
        if (t == 0) *flag = (bad == 0) ? 1 : 0;
    }
    for (int i = gid; i < NNODE * 512 / 4; i += nthr) {
        float4 v = ((const float4*)x)[i];
        half4 h;
        h[0] = (_Float16)v.x; h[1] = (_Float16)v.y;
        h[2] = (_Float16)v.z; h[3] = (_Float16)v.w;
        *(half4*)&xh[4 * (size_t)i] = h;
    }
    for (int i = gid; i < 512 * NHID; i += nthr) {
        int k = i >> 8, n = i & 255;
        w1T[(size_t)n * 512 + k] = (_Float16)W1[i];
    }
    for (int i = gid; i < NHID * NHID; i += nthr) {
        int k = i >> 8, n = i & 255;
        w2T[(size_t)n * 256 + k] = (_Float16)W2[i];
    }
}

// ---------------------------------------------------------------- S1: gemm1 (first half) ∥ scatter (second half)
__device__ __forceinline__ void stage_s1(
    char* smem, int bid, int nb, int t,
    const void* edges, const int* flag, int* rowcnt, int* nbr, int* deg, int E,
    const _Float16* __restrict__ xh, const _Float16* __restrict__ w1T, _Float16* __restrict__ X1) {
    const int ng = nb >> 1;
    if (bid < ng) {
        for (int g = bid; g < 512; g += ng)
            gemm_body(smem, xh, w1T, X1, 512, (g >> 2) * 64, (g & 3) * 64);
    } else {
        const int ns = nb - ng;
        const int fl = *flag;
        const int total = E + NNODE;
        for (int i = (bid - ng) * 256 + t; i < total; i += ns * 256) {
            int r, c;
            if (i < E) {
                if (fl) {
                    const long long* e = (const long long*)edges;
                    r = (int)e[i]; c = (int)e[E + i];
                } else {
                    const int* e = (const int*)edges;
                    r = e[i]; c = e[E + i];
                }
            } else { r = i - E; c = r; }
            int pos = atomicAdd(&rowcnt[r], 1);
            if (pos < RCAP) nbr[r * RCAP + pos] = c;
            atomicAdd(&deg[c], 1);
        }
    }
}

// ================================================================ cooperative mega-kernel (any grid size)
__global__ __launch_bounds__(256, 4) void k_mega(
    const float* __restrict__ x, const void* edges,
    const float* __restrict__ W1, const float* __restrict__ b1,
    const float* __restrict__ W2, const float* __restrict__ b2,
    float* __restrict__ out,
    int* deg, int* rowcnt, int* flag, int* nbr, int* cols, float* wA,
    float* rsum, _Float16* xh, _Float16* w1T, _Float16* w2T,
    _Float16* X1, _Float16* Hh, int E) {
    cg::grid_group grid = cg::this_grid();
    __shared__ __align__(16) char smem[sizeof(SmemMedoid)];
    const int nb = gridDim.x, bid = blockIdx.x, t = threadIdx.x;
    const int gid = bid * 256 + t, nthr = nb * 256;

    stage_prep(gid, nthr, bid, t, deg, rowcnt, flag, edges, x, xh, W1, w1T, W2, w2T);
    grid.sync();
    stage_s1(smem, bid, nb, t, edges, flag, rowcnt, nbr, deg, E, xh, w1T, X1);
    grid.sync();
    for (int g = bid; g < NNODE / 2; g += nb)
        dedup_body(smem, nbr, rowcnt, deg, cols, wA, rsum, g);
    grid.sync();
    for (int node = bid; node < NNODE; node += nb)
        medoid_body(smem, X1, b1, nullptr, Hh, cols, wA, rsum, node, 1);
    grid.sync();
    for (int g = bid; g < 512; g += nb)
        gemm_body(smem, Hh, w2T, X1, 256, (g >> 2) * 64, (g & 3) * 64);
    grid.sync();
    for (int node = bid; node < NNODE; node += nb)
        medoid_body(smem, X1, b2, out, nullptr, cols, wA, rsum, node, 0);
}

// ================================================================ fallback kernels (same bodies)
__global__ __launch_bounds__(256) void fb_prep(
    int* deg, int* rowcnt, int* flag, const void* edges,
    const float* __restrict__ x, _Float16* __restrict__ xh,
    const float* __restrict__ W1, _Float16* __restrict__ w1T,
    const float* __restrict__ W2, _Float16* __restrict__ w2T) {
    stage_prep(blockIdx.x * 256 + threadIdx.x, gridDim.x * 256, blockIdx.x, threadIdx.x,
               deg, rowcnt, flag, edges, x, xh, W1, w1T, W2, w2T);
}

__global__ __launch_bounds__(256) void fb_s1(
    const void* edges, const int* flag, int* rowcnt, int* nbr, int* deg, int E,
    const _Float16* __restrict__ xh, const _Float16* __restrict__ w1T, _Float16* __restrict__ X1) {
    __shared__ __align__(16) char smem[sizeof(SmemGemm)];
    stage_s1(smem, blockIdx.x, gridDim.x, threadIdx.x, edges, flag, rowcnt, nbr, deg, E, xh, w1T, X1);
}

__global__ __launch_bounds__(256) void fb_dedup(
    const int* __restrict__ nbr, const int* __restrict__ rowcnt, const int* __restrict__ deg,
    int* __restrict__ cols, float* __restrict__ wout, float* __restrict__ rsum) {
    __shared__ __align__(16) char smem[sizeof(SmemDedup)];
    for (int g = blockIdx.x; g < NNODE / 2; g += gridDim.x)
        dedup_body(smem, nbr, rowcnt, deg, cols, wout, rsum, g);
}

__global__ __launch_bounds__(256, 4) void fb_medoid(
    const _Float16* __restrict__ Xhi, const float* __restrict__ bias,
    float* __restrict__ OutF, _Float16* __restrict__ OutHi,
    const int* __restrict__ cols, const float* __restrict__ wts,
    const float* __restrict__ rsum, int writeH) {
    __shared__ __align__(16) char smem[sizeof(SmemMedoid)];
    for (int node = blockIdx.x; node < NNODE; node += gridDim.x)
        medoid_body(smem, Xhi, bias, OutF, OutHi, cols, wts, rsum, node, writeH);
}

__global__ __launch_bounds__(256) void fb_gemm(
    const _Float16* __restrict__ Ahi, const _Float16* __restrict__ BT,
    _Float16* __restrict__ Chi, int K) {
    __shared__ __align__(16) char smem[sizeof(SmemGemm)];
    for (int g = blockIdx.x; g < 512; g += gridDim.x)
        gemm_body(smem, Ahi, BT, Chi, K, (g >> 2) * 64, (g & 3) * 64);
}

// ================================================================ launch
extern "C" void kernel_launch(void* const* d_in, const int* in_sizes, int n_in,
                              void* d_out, int out_size, void* d_ws, size_t ws_size,
                              hipStream_t stream) {
    const float* x  = (const float*)d_in[0];
    const void*  ei = d_in[1];
    const float* W1 = (const float*)d_in[2];
    const float* b1 = (const float*)d_in[3];
    const float* W2 = (const float*)d_in[4];
    const float* b2 = (const float*)d_in[5];
    float* out = (float*)d_out;
    int E = in_sizes[1] / 2;

    char* p = (char*)d_ws;
    auto alloc = [&](size_t bytes) { char* q = p; p += (bytes + 255) & ~(size_t)255; return q; };
    int*      deg    = (int*)alloc((size_t)NNODE * 4);
    int*      rowcnt = (int*)alloc((size_t)NNODE * 4);
    int*      flag   = (int*)alloc(256);
    int*      colsA  = (int*)alloc((size_t)NNODE * KCAP * 4);
    float*    wA     = (float*)alloc((size_t)NNODE * KCAP * 4);
    float*    rsum   = (float*)alloc((size_t)NNODE * 4);
    _Float16* xh     = (_Float16*)alloc((size_t)NNODE * 512 * 2);
    _Float16* w1T    = (_Float16*)alloc((size_t)512 * NHID * 2);
    _Float16* w2T    = (_Float16*)alloc((size_t)NHID * NHID * 2);
    _Float16* X1     = (_Float16*)alloc((size_t)NNODE * NHID * 2);   // also X2
    _Float16* Hh     = (_Float16*)alloc((size_t)NNODE * NHID * 2);
    int*      nbr    = (int*)alloc((size_t)NNODE * RCAP * 4);

    // capability + occupancy queries (host-only, capture-safe)
    int dev = 0; hipGetDevice(&dev);
    int coopAttr = 0;
    hipDeviceGetAttribute(&coopAttr, hipDeviceAttributeCooperativeLaunch, dev);
    int ncu = 0;
    hipDeviceGetAttribute(&ncu, hipDeviceAttributeMultiprocessorCount, dev);
    if (ncu <= 0) ncu = 256;
    int maxb = 0;
    hipError_t qe = hipOccupancyMaxActiveBlocksPerMultiprocessor(
        &maxb, (const void*)k_mega, 256, 0);

    hipError_t le = hipErrorUnknown;
    if (coopAttr != 0 && qe == hipSuccess && maxb >= 1) {
        int nblk = maxb * ncu;
        if (nblk > 2048) nblk = 2048;
        if (nblk >= 64) {
            void* args[] = {
                (void*)&x, (void*)&ei, (void*)&W1, (void*)&b1, (void*)&W2, (void*)&b2,
                (void*)&out, (void*)&deg, (void*)&rowcnt, (void*)&flag, (void*)&nbr,
                (void*)&colsA, (void*)&wA, (void*)&rsum, (void*)&xh, (void*)&w1T,
                (void*)&w2T, (void*)&X1, (void*)&Hh, (void*)&E
            };
            le = hipLaunchCooperativeKernel((const void*)k_mega, dim3(nblk), dim3(256),
                                            args, 0, stream);
        }
    }
    if (le != hipSuccess) {
        // deterministic fallback: proven 6-dispatch path, same device bodies
        fb_prep<<<1024, 256, 0, stream>>>(deg, rowcnt, flag, ei, x, xh, W1, w1T, W2, w2T);
        fb_s1<<<1024, 256, 0, stream>>>(ei, flag, rowcnt, nbr, deg, E, xh, w1T, X1);
        fb_dedup<<<NNODE / 2, 256, 0, stream>>>(nbr, rowcnt, deg, colsA, wA, rsum);
        fb_medoid<<<NNODE, 256, 0, stream>>>(X1, b1, nullptr, Hh, colsA, wA, rsum, 1);
        fb_gemm<<<512, 256, 0, stream>>>(Hh, w2T, X1, 256);
        fb_medoid<<<NNODE, 256, 0, stream>>>(X1, b2, out, nullptr, colsA, wA, rsum, 0);
    }
}

// Round 11
// 220.741 us; speedup vs baseline: 2.7153x; 2.7153x over previous
//
#include <hip/hip_runtime.h>

typedef _Float16 half4 __attribute__((ext_vector_type(4)));
typedef _Float16 half8 __attribute__((ext_vector_type(8)));
typedef float f32x4 __attribute__((ext_vector_type(4)));

#define NNODE 8192
#define NHID  256
#define RCAP  128
#define KCAP  64
#define GLS   72    // gemm lds row stride (fp16): 144B = 9 quads, conflict-free
#define SK    136   // medoid lds row stride (fp16): 272B = 17 quads, conflict-free

struct SmemGemm { _Float16 sA[64][GLS]; _Float16 sB[64][GLS]; };

struct DedupScratch {
    int lc[RCAP]; float lw[RCAP]; unsigned char kp[RCAP];
    int cw[2]; float rw[2];
};

struct SmemMedoid {
    union { _Float16 sh[64][SK]; DedupScratch dd; } u;   // dd dead before sh gather
    float s_a[64]; float s_sq[64]; float s_cpart[2][64]; float s_u[64];
    int s_cols[64]; float s_red[4][288]; float s_rsum;
};

// ---------------------------------------------------------------- GEMM tile body
// C[M x 256] = A[M x K] * W[K x 256].  A: fp32 (convert in staging) or fp16.
// B staged from fp32 W with transpose-in-LDS (coalesced global loads).
__device__ __forceinline__ void gemm_body(
    char* smraw, const float* __restrict__ Af32, const _Float16* __restrict__ Ahi,
    const float* __restrict__ W, _Float16* __restrict__ Chi,
    int K, int af32, int bm, int bn) {
    SmemGemm& sm = *(SmemGemm*)smraw;
    const int t = threadIdx.x;
    const int lane = t & 63, L15 = lane & 15, q = lane >> 4;
    const int w = t >> 6, wr = w >> 1, wc = w & 1;
    f32x4 acc[2][2];
#pragma unroll
    for (int a = 0; a < 2; ++a)
#pragma unroll
        for (int b2 = 0; b2 < 2; ++b2) acc[a][b2] = (f32x4){0.f, 0.f, 0.f, 0.f};

    for (int k0 = 0; k0 < K; k0 += 64) {
        if (af32) {
#pragma unroll
            for (int i = 0; i < 4; ++i) {
                int row = i * 16 + (t >> 4), kc = (t & 15) * 4;
                float4 v = *(const float4*)(Af32 + (size_t)(bm + row) * K + k0 + kc);
                half4 h;
                h[0] = (_Float16)v.x; h[1] = (_Float16)v.y;
                h[2] = (_Float16)v.z; h[3] = (_Float16)v.w;
                *(half4*)&sm.sA[row][kc] = h;
            }
        } else {
#pragma unroll
            for (int i = 0; i < 2; ++i) {
                int row = i * 32 + (t >> 3), ch = t & 7;
                *(half8*)&sm.sA[row][ch * 8] =
                    *(const half8*)(Ahi + (size_t)(bm + row) * K + k0 + ch * 8);
            }
        }
        // B: sB[n][k] = W[k0+k][bn+n], coalesced fp32 loads + transposed half stores
#pragma unroll
        for (int i = 0; i < 4; ++i) {
            int krow = i * 16 + (t >> 4), nc4 = (t & 15) * 4;
            float4 v = *(const float4*)(W + (size_t)(k0 + krow) * NHID + bn + nc4);
            sm.sB[nc4 + 0][krow] = (_Float16)v.x;
            sm.sB[nc4 + 1][krow] = (_Float16)v.y;
            sm.sB[nc4 + 2][krow] = (_Float16)v.z;
            sm.sB[nc4 + 3][krow] = (_Float16)v.w;
        }
        __syncthreads();
#pragma unroll
        for (int ks = 0; ks < 2; ++ks) {
            const int ko = ks * 32 + q * 8;
            half8 ah[2], bh[2];
#pragma unroll
            for (int tr = 0; tr < 2; ++tr)
                ah[tr] = *(const half8*)&sm.sA[32 * wr + 16 * tr + L15][ko];
#pragma unroll
            for (int tc = 0; tc < 2; ++tc)
                bh[tc] = *(const half8*)&sm.sB[32 * wc + 16 * tc + L15][ko];
#pragma unroll
            for (int tr = 0; tr < 2; ++tr)
#pragma unroll
                for (int tc = 0; tc < 2; ++tc)
                    acc[tr][tc] = __builtin_amdgcn_mfma_f32_16x16x32_f16(ah[tr], bh[tc], acc[tr][tc], 0, 0, 0);
        }
        __syncthreads();
    }
#pragma unroll
    for (int tr = 0; tr < 2; ++tr)
#pragma unroll
        for (int tc = 0; tc < 2; ++tc)
#pragma unroll
            for (int r = 0; r < 4; ++r) {
                int rowg = bm + 32 * wr + 16 * tr + q * 4 + r;
                int colg = bn + 32 * wc + 16 * tc + L15;
                Chi[(size_t)rowg * NHID + colg] = (_Float16)acc[tr][tc][r];
            }
}

// ---------------------------------------------------------------- medoid core
// Assumes sm.s_cols / sm.s_a / sm.s_rsum are populated and barrier'd.
__device__ __forceinline__ void medoid_core(
    SmemMedoid& sm, const _Float16* __restrict__ Xhi, const float* __restrict__ bias,
    float* __restrict__ OutF, _Float16* __restrict__ OutHi, int node, int writeH) {
    const int t = threadIdx.x;
    const int w = t >> 6, lane = t & 63;
    const int L15 = lane & 15, q = lane >> 4;
    const int wr = w >> 1, wc = w & 1;

    f32x4 acc[2][2];
#pragma unroll
    for (int a = 0; a < 2; ++a)
#pragma unroll
        for (int b = 0; b < 2; ++b) acc[a][b] = (f32x4){0.f, 0.f, 0.f, 0.f};

    const int ch = t & 15, rr = t >> 4;
    for (int phase = 0; phase < 2; ++phase) {
#pragma unroll
        for (int i = 0; i < 4; ++i) {
            int l = i * 16 + rr;
            *(half8*)&sm.u.sh[l][ch * 8] =
                *(const half8*)(Xhi + ((size_t)sm.s_cols[l] << 8) + phase * 128 + ch * 8);
        }
        __syncthreads();
#pragma unroll
        for (int ks = 0; ks < 4; ++ks) {
            const int ko = ks * 32 + q * 8;
            half8 ah[2], bh[2];
#pragma unroll
            for (int tr = 0; tr < 2; ++tr) ah[tr] = *(const half8*)&sm.u.sh[32 * wr + 16 * tr + L15][ko];
#pragma unroll
            for (int tc = 0; tc < 2; ++tc) bh[tc] = *(const half8*)&sm.u.sh[32 * wc + 16 * tc + L15][ko];
#pragma unroll
            for (int tr = 0; tr < 2; ++tr)
#pragma unroll
                for (int tc = 0; tc < 2; ++tc)
                    acc[tr][tc] = __builtin_amdgcn_mfma_f32_16x16x32_f16(ah[tr], bh[tc], acc[tr][tc], 0, 0, 0);
        }
        if (phase == 0) __syncthreads();
    }
    // sm.u.sh holds dims 128..255 for the epilogue

#pragma unroll
    for (int tr = 0; tr < 2; ++tr)
#pragma unroll
        for (int tc = 0; tc < 2; ++tc)
            if (32 * wr + 16 * tr == 32 * wc + 16 * tc) {
#pragma unroll
                for (int r = 0; r < 4; ++r)
                    if (L15 == q * 4 + r) sm.s_sq[32 * wr + 16 * tr + L15] = acc[tr][tc][r];
            }
    __syncthreads();

    f32x4 sq4[2], a4[2];
#pragma unroll
    for (int tr = 0; tr < 2; ++tr) {
        sq4[tr] = *(const f32x4*)&sm.s_sq[32 * wr + 16 * tr + 4 * q];
        a4[tr]  = *(const f32x4*)&sm.s_a [32 * wr + 16 * tr + 4 * q];
    }
#pragma unroll
    for (int tc = 0; tc < 2; ++tc) {
        const int colg = 32 * wc + 16 * tc + L15;
        const float sqc = sm.s_sq[colg];
        float pj = 0.f;
#pragma unroll
        for (int tr = 0; tr < 2; ++tr)
#pragma unroll
            for (int r = 0; r < 4; ++r) {
                float d2 = sq4[tr][r] + sqc - 2.f * acc[tr][tc][r];
                float dist = d2 > 0.f ? __builtin_amdgcn_sqrtf(d2) : 0.f;
                pj = fmaf(a4[tr][r], dist, pj);
            }
        pj += __shfl_xor(pj, 16, 64);
        pj += __shfl_xor(pj, 32, 64);
        if (q == 0) sm.s_cpart[wr][colg] = pj;
    }
    __syncthreads();

    if (w == 0) {
        int j = lane;
        float c = sm.s_cpart[0][j] + sm.s_cpart[1][j];
        float aj = sm.s_a[j];
        bool valid = aj > 0.f;
        float cv = valid ? c : 3.4e38f;
        float mn = cv;
#pragma unroll
        for (int d = 1; d < 64; d <<= 1) mn = fminf(mn, __shfl_xor(mn, d, 64));
        float e = valid ? __expf(mn - c) * aj : 0.f;
        float s = e;
#pragma unroll
        for (int d = 1; d < 64; d <<= 1) s += __shfl_xor(s, d, 64);
        sm.s_u[j] = e * (sm.s_rsum / s);
    }
    __syncthreads();

    const int oct = t & 31, jb = t >> 5;
    float accd[8] = {0.f, 0.f, 0.f, 0.f, 0.f, 0.f, 0.f, 0.f};
#pragma unroll
    for (int jj = 0; jj < 8; ++jj) {
        int j = jb * 8 + jj;
        float u = sm.s_u[j];
        half8 xv;
        if (oct < 16) xv = *(const half8*)(Xhi + ((size_t)sm.s_cols[j] << 8) + oct * 8);
        else          xv = *(const half8*)&sm.u.sh[j][(oct - 16) * 8];
#pragma unroll
        for (int e = 0; e < 8; ++e) accd[e] = fmaf(u, (float)xv[e], accd[e]);
    }
#pragma unroll
    for (int e = 0; e < 8; ++e) accd[e] += __shfl_xor(accd[e], 32, 64);
    if (lane < 32) {
#pragma unroll
        for (int e = 0; e < 8; ++e) sm.s_red[w][9 * oct + e] = accd[e];
    }
    __syncthreads();
    const int idx = 9 * (t >> 3) + (t & 7);
    float o = sm.s_red[0][idx] + sm.s_red[1][idx] + sm.s_red[2][idx] + sm.s_red[3][idx];
    float res = fmaxf(o + bias[t], 0.f);
    size_t oi = (size_t)node * NHID + t;
    if (writeH) OutHi[oi] = (_Float16)res;
    else        OutF[oi] = res;
}

// ================================================================ D1: gemm1 (blocks 0..511) ∥ edge scatter
__global__ __launch_bounds__(256) void k_s1(
    const float* __restrict__ x, const float* __restrict__ W1, const void* edges,
    int* rowcnt, int* nbr, int* deg, int E, _Float16* __restrict__ X1) {
    if ((int)blockIdx.x < 512) {
        __shared__ __align__(16) char smem[sizeof(SmemGemm)];
        int g = blockIdx.x;
        gemm_body(smem, x, nullptr, W1, X1, 512, 1, (g >> 2) * 64, (g & 3) * 64);
    } else {
        __shared__ int sflag;
        const int t = threadIdx.x;
        if (t < 64) {   // per-block dtype probe (L2-hot after first block)
            const long long* e = (const long long*)edges;
            long long v = e[t];
            unsigned long long bad = __ballot(v < 0 || v >= (long long)NNODE);
            if (t == 0) sflag = (bad == 0) ? 1 : 0;
        }
        __syncthreads();
        const int fl = sflag;
        int i = ((int)blockIdx.x - 512) * 256 + t;
        if (i >= E + NNODE) return;
        int r, c;
        if (i < E) {
            if (fl) {
                const long long* e = (const long long*)edges;
                r = (int)e[i]; c = (int)e[E + i];
            } else {
                const int* e = (const int*)edges;
                r = e[i]; c = e[E + i];
            }
        } else { r = i - E; c = r; }   // self loop
        int pos = atomicAdd(&rowcnt[r], 1);
        if (pos < RCAP) nbr[r * RCAP + pos] = c;
        atomicAdd(&deg[c], 1);
    }
}

// ================================================================ D2: dedup + medoid layer 1
__global__ __launch_bounds__(256, 6) void k_medoid1(
    const _Float16* __restrict__ X, const float* __restrict__ b1,
    _Float16* __restrict__ Hh,
    const int* __restrict__ nbr, const int* __restrict__ rowcnt,
    const int* __restrict__ deg,
    int* __restrict__ cols, float* __restrict__ wA, float* __restrict__ rsum) {
    __shared__ __align__(16) SmemMedoid sm;
    const int r = blockIdx.x, t = threadIdx.x;
    const int w = t >> 6, lane = t & 63;

    // ---- dedup prologue (this node only)
    int n = rowcnt[r]; if (n > RCAP) n = RCAP;
    if (t < n) sm.u.dd.lc[t] = nbr[r * RCAP + t];
    __syncthreads();
    float dr = 1.f / sqrtf((float)deg[r]);
    bool keep = false; float wv = 0.f; int myc = 0;
    if (t < n) {
        myc = sm.u.dd.lc[t];
        int mult = 0; bool first = true;
        for (int i = 0; i < n; ++i) {
            int ci = sm.u.dd.lc[i];
            if (ci == myc) { mult++; if (i < t) first = false; }
        }
        keep = first;
        if (first) wv = (float)mult * dr * (1.f / sqrtf((float)deg[myc]));
    }
    if (t < RCAP) { sm.u.dd.kp[t] = keep ? 1 : 0; sm.u.dd.lw[t] = wv; }
    int pre = 0;
    if (w < 2) {
        float rv = wv;
#pragma unroll
        for (int d = 1; d < 64; d <<= 1) rv += __shfl_xor(rv, d, 64);
        unsigned long long b = __ballot(keep);
        pre = __popcll(b & ((1ull << lane) - 1ull));
        int cw = __popcll(b);
        if (lane == 0) { sm.u.dd.cw[w] = cw; sm.u.dd.rw[w] = rv; }
    }
    __syncthreads();
    int total = sm.u.dd.cw[0] + sm.u.dd.cw[1];
    float rs = sm.u.dd.rw[0] + sm.u.dd.rw[1];
    if (t == 0) { rsum[r] = rs; sm.s_rsum = rs; }
    const int base = r * KCAP;
    if (total <= KCAP) {
        if (w < 2 && keep) {
            int off = (w ? sm.u.dd.cw[0] : 0) + pre;
            cols[base + off] = myc; wA[base + off] = wv;
            sm.s_cols[off] = myc;   sm.s_a[off] = wv;
        }
        for (int m = total + t; m < KCAP; m += 256) {
            cols[base + m] = r; wA[base + m] = 0.f;
            sm.s_cols[m] = r;   sm.s_a[m] = 0.f;
        }
    } else if (t == 0) {   // ultra-rare: top-64 by (weight desc, col asc)
        for (int s = 0; s < KCAP; ++s) {
            int best = -1;
            for (int i = 0; i < n; ++i) {
                if (!sm.u.dd.kp[i]) continue;
                if (best < 0 || sm.u.dd.lw[i] > sm.u.dd.lw[best] ||
                    (sm.u.dd.lw[i] == sm.u.dd.lw[best] && sm.u.dd.lc[i] < sm.u.dd.lc[best])) best = i;
            }
            cols[base + s] = sm.u.dd.lc[best]; wA[base + s] = sm.u.dd.lw[best];
            sm.s_cols[s] = sm.u.dd.lc[best];   sm.s_a[s] = sm.u.dd.lw[best];
            sm.u.dd.kp[best] = 0;
        }
    }
    __syncthreads();   // dd dead; sh may now be written

    medoid_core(sm, X, b1, nullptr, Hh, r, 1);
}

// ================================================================ D3: gemm layer 2
__global__ __launch_bounds__(256) void k_gemm2(
    const _Float16* __restrict__ Hh, const float* __restrict__ W2,
    _Float16* __restrict__ X2) {
    __shared__ __align__(16) char smem[sizeof(SmemGemm)];
    gemm_body(smem, nullptr, Hh, W2, X2, 256, 0, blockIdx.x * 64, blockIdx.y * 64);
}

// ================================================================ D4: medoid layer 2
__global__ __launch_bounds__(256, 6) void k_medoid2(
    const _Float16* __restrict__ X, const float* __restrict__ b2,
    float* __restrict__ out,
    const int* __restrict__ cols, const float* __restrict__ wts,
    const float* __restrict__ rsum) {
    __shared__ __align__(16) SmemMedoid sm;
    const int node = blockIdx.x, t = threadIdx.x;
    if (t < 64) { sm.s_cols[t] = cols[node * KCAP + t]; sm.s_a[t] = wts[node * KCAP + t]; }
    if (t == 0) sm.s_rsum = rsum[node];
    __syncthreads();
    medoid_core(sm, X, b2, out, nullptr, node, 0);
}

// ================================================================ launch
extern "C" void kernel_launch(void* const* d_in, const int* in_sizes, int n_in,
                              void* d_out, int out_size, void* d_ws, size_t ws_size,
                              hipStream_t stream) {
    const float* x  = (const float*)d_in[0];
    const void*  ei = d_in[1];
    const float* W1 = (const float*)d_in[2];
    const float* b1 = (const float*)d_in[3];
    const float* W2 = (const float*)d_in[4];
    const float* b2 = (const float*)d_in[5];
    float* out = (float*)d_out;
    const int E = in_sizes[1] / 2;

    char* p = (char*)d_ws;
    auto alloc = [&](size_t bytes) { char* q = p; p += (bytes + 255) & ~(size_t)255; return q; };
    int*      cnt   = (int*)alloc((size_t)2 * NNODE * 4);   // deg | rowcnt (one memset)
    int*      deg    = cnt;
    int*      rowcnt = cnt + NNODE;
    int*      colsA  = (int*)alloc((size_t)NNODE * KCAP * 4);
    float*    wAr    = (float*)alloc((size_t)NNODE * KCAP * 4);
    float*    rsum   = (float*)alloc((size_t)NNODE * 4);
    _Float16* X1     = (_Float16*)alloc((size_t)NNODE * NHID * 2);   // also X2
    _Float16* Hh     = (_Float16*)alloc((size_t)NNODE * NHID * 2);
    int*      nbr    = (int*)alloc((size_t)NNODE * RCAP * 4);

    const int nscat = (E + NNODE + 255) / 256;

    hipMemsetAsync(cnt, 0, (size_t)2 * NNODE * 4, stream);
    k_s1<<<512 + nscat, 256, 0, stream>>>(x, W1, ei, rowcnt, nbr, deg, E, X1);
    k_medoid1<<<NNODE, 256, 0, stream>>>(X1, b1, Hh, nbr, rowcnt, deg, colsA, wAr, rsum);
    k_gemm2<<<dim3(NNODE / 64, NHID / 64), 256, 0, stream>>>(Hh, W2, X1);
    k_medoid2<<<NNODE, 256, 0, stream>>>(X1, b2, out, colsA, wAr, rsum);
}

// Round 12
// 213.126 us; speedup vs baseline: 2.8123x; 1.0357x over previous
//
#include <hip/hip_runtime.h>

typedef _Float16 half4 __attribute__((ext_vector_type(4)));
typedef _Float16 half8 __attribute__((ext_vector_type(8)));
typedef float f32x4 __attribute__((ext_vector_type(4)));

#define NNODE 8192
#define NHID  256
#define RCAP  128
#define KCAP  64
#define GLS   72    // gemm lds row stride (fp16): 144B = 9 quads, conflict-free
#define SK    136   // medoid lds row stride (fp16): 272B = 17 quads, conflict-free

struct SmemGemm  { _Float16 sA[64][GLS]; _Float16 sB[64][GLS]; };
struct SmemDedup { int lc[2][RCAP]; float lw[2][RCAP]; unsigned char kp[2][RCAP];
                   int cw[2][2]; float rw[2][2]; };
struct SmemMedoid {
    _Float16 sh[64][SK];
    float s_a[64]; float s_sq[64]; float s_cpart[2][64]; float s_u[64];
    int s_cols[64]; float s_red[4][288]; float s_rsum;
};

// ---------------------------------------------------------------- GEMM tile body (fp16 A, fp16 BT)
__device__ __forceinline__ void gemm_body(
    char* smraw, const _Float16* __restrict__ Ahi, const _Float16* __restrict__ BT,
    _Float16* __restrict__ Chi, int K, int bm, int bn) {
    SmemGemm& sm = *(SmemGemm*)smraw;
    const int t = threadIdx.x;
    const int lane = t & 63, L15 = lane & 15, q = lane >> 4;
    const int w = t >> 6, wr = w >> 1, wc = w & 1;
    f32x4 acc[2][2];
#pragma unroll
    for (int a = 0; a < 2; ++a)
#pragma unroll
        for (int b2 = 0; b2 < 2; ++b2) acc[a][b2] = (f32x4){0.f, 0.f, 0.f, 0.f};

    for (int k0 = 0; k0 < K; k0 += 64) {
#pragma unroll
        for (int i = 0; i < 2; ++i) {
            int row = i * 32 + (t >> 3), ch = t & 7;
            *(half8*)&sm.sA[row][ch * 8] =
                *(const half8*)(Ahi + (size_t)(bm + row) * K + k0 + ch * 8);
            *(half8*)&sm.sB[row][ch * 8] =
                *(const half8*)(BT + (size_t)(bn + row) * K + k0 + ch * 8);
        }
        __syncthreads();
#pragma unroll
        for (int ks = 0; ks < 2; ++ks) {
            const int ko = ks * 32 + q * 8;
            half8 ah[2], bh[2];
#pragma unroll
            for (int tr = 0; tr < 2; ++tr)
                ah[tr] = *(const half8*)&sm.sA[32 * wr + 16 * tr + L15][ko];
#pragma unroll
            for (int tc = 0; tc < 2; ++tc)
                bh[tc] = *(const half8*)&sm.sB[32 * wc + 16 * tc + L15][ko];
#pragma unroll
            for (int tr = 0; tr < 2; ++tr)
#pragma unroll
                for (int tc = 0; tc < 2; ++tc)
                    acc[tr][tc] = __builtin_amdgcn_mfma_f32_16x16x32_f16(ah[tr], bh[tc], acc[tr][tc], 0, 0, 0);
        }
        __syncthreads();
    }
#pragma unroll
    for (int tr = 0; tr < 2; ++tr)
#pragma unroll
        for (int tc = 0; tc < 2; ++tc)
#pragma unroll
            for (int r = 0; r < 4; ++r) {
                int rowg = bm + 32 * wr + 16 * tr + q * 4 + r;
                int colg = bn + 32 * wc + 16 * tc + L15;
                Chi[(size_t)rowg * NHID + colg] = (_Float16)acc[tr][tc][r];
            }
}

// ---------------------------------------------------------------- dedup body (2 rows per call)
__device__ __forceinline__ void dedup_body(
    char* smraw, const int* __restrict__ nbr, const int* __restrict__ rowcnt,
    const int* __restrict__ deg, int* __restrict__ cols, float* __restrict__ wout,
    float* __restrict__ rsum, int grp) {
    SmemDedup& sm = *(SmemDedup*)smraw;
    const int t = threadIdx.x;
    const int half = t >> 7, st = t & 127;
    const int wid = st >> 6, lane = t & 63;
    const int r = grp * 2 + half;
    int n = rowcnt[r]; if (n > RCAP) n = RCAP;
    if (st < n) sm.lc[half][st] = nbr[r * RCAP + st];
    __syncthreads();
    float dr = 1.f / sqrtf((float)deg[r]);
    bool keep = false; float wv = 0.f;
    if (st < n) {
        int c = sm.lc[half][st];
        int mult = 0; bool first = true;
        for (int i = 0; i < n; ++i) {
            int ci = sm.lc[half][i];
            if (ci == c) { mult++; if (i < st) first = false; }
        }
        keep = first;
        if (first) wv = (float)mult * dr * (1.f / sqrtf((float)deg[c]));
    }
    sm.kp[half][st] = keep ? 1 : 0; sm.lw[half][st] = wv;
    float rv = wv;
#pragma unroll
    for (int d = 1; d < 64; d <<= 1) rv += __shfl_xor(rv, d, 64);
    unsigned long long b = __ballot(keep);
    int pre = __popcll(b & ((1ull << lane) - 1ull));
    int cw = __popcll(b);
    if (lane == 0) { sm.cw[half][wid] = cw; sm.rw[half][wid] = rv; }
    __syncthreads();
    int total = sm.cw[half][0] + sm.cw[half][1];
    if (st == 0) rsum[r] = sm.rw[half][0] + sm.rw[half][1];
    const int base = r * KCAP;
    if (total <= KCAP) {
        int off = (wid ? sm.cw[half][0] : 0) + pre;
        if (keep) { cols[base + off] = sm.lc[half][st]; wout[base + off] = wv; }
        for (int m = total + st; m < KCAP; m += 128) { cols[base + m] = r; wout[base + m] = 0.f; }
    } else if (st == 0) {
        for (int s = 0; s < KCAP; ++s) {
            int best = -1;
            for (int i = 0; i < n; ++i) {
                if (!sm.kp[half][i]) continue;
                if (best < 0 || sm.lw[half][i] > sm.lw[half][best] ||
                    (sm.lw[half][i] == sm.lw[half][best] && sm.lc[half][i] < sm.lc[half][best])) best = i;
            }
            cols[base + s] = sm.lc[half][best]; wout[base + s] = sm.lw[half][best]; sm.kp[half][best] = 0;
        }
    }
}

// ---------------------------------------------------------------- medoid core (s_cols/s_a/s_rsum pre-loaded)
__device__ __forceinline__ void medoid_core(
    SmemMedoid& sm, const _Float16* __restrict__ Xhi, const float* __restrict__ bias,
    float* __restrict__ OutF, _Float16* __restrict__ OutHi, int node, int writeH) {
    const int t = threadIdx.x;
    const int w = t >> 6, lane = t & 63;
    const int L15 = lane & 15, q = lane >> 4;
    const int wr = w >> 1, wc = w & 1;

    f32x4 acc[2][2];
#pragma unroll
    for (int a = 0; a < 2; ++a)
#pragma unroll
        for (int b = 0; b < 2; ++b) acc[a][b] = (f32x4){0.f, 0.f, 0.f, 0.f};

    const int ch = t & 15, rr = t >> 4;
    for (int phase = 0; phase < 2; ++phase) {
#pragma unroll
        for (int i = 0; i < 4; ++i) {
            int l = i * 16 + rr;
            *(half8*)&sm.sh[l][ch * 8] =
                *(const half8*)(Xhi + ((size_t)sm.s_cols[l] << 8) + phase * 128 + ch * 8);
        }
        __syncthreads();
#pragma unroll
        for (int ks = 0; ks < 4; ++ks) {
            const int ko = ks * 32 + q * 8;
            half8 ah[2], bh[2];
#pragma unroll
            for (int tr = 0; tr < 2; ++tr) ah[tr] = *(const half8*)&sm.sh[32 * wr + 16 * tr + L15][ko];
#pragma unroll
            for (int tc = 0; tc < 2; ++tc) bh[tc] = *(const half8*)&sm.sh[32 * wc + 16 * tc + L15][ko];
#pragma unroll
            for (int tr = 0; tr < 2; ++tr)
#pragma unroll
                for (int tc = 0; tc < 2; ++tc)
                    acc[tr][tc] = __builtin_amdgcn_mfma_f32_16x16x32_f16(ah[tr], bh[tc], acc[tr][tc], 0, 0, 0);
        }
        if (phase == 0) __syncthreads();
    }
    // sm.sh holds dims 128..255 for the epilogue

#pragma unroll
    for (int tr = 0; tr < 2; ++tr)
#pragma unroll
        for (int tc = 0; tc < 2; ++tc)
            if (32 * wr + 16 * tr == 32 * wc + 16 * tc) {
#pragma unroll
                for (int r = 0; r < 4; ++r)
                    if (L15 == q * 4 + r) sm.s_sq[32 * wr + 16 * tr + L15] = acc[tr][tc][r];
            }
    __syncthreads();

    f32x4 sq4[2], a4[2];
#pragma unroll
    for (int tr = 0; tr < 2; ++tr) {
        sq4[tr] = *(const f32x4*)&sm.s_sq[32 * wr + 16 * tr + 4 * q];
        a4[tr]  = *(const f32x4*)&sm.s_a [32 * wr + 16 * tr + 4 * q];
    }
#pragma unroll
    for (int tc = 0; tc < 2; ++tc) {
        const int colg = 32 * wc + 16 * tc + L15;
        const float sqc = sm.s_sq[colg];
        float pj = 0.f;
#pragma unroll
        for (int tr = 0; tr < 2; ++tr)
#pragma unroll
            for (int r = 0; r < 4; ++r) {
                float d2 = sq4[tr][r] + sqc - 2.f * acc[tr][tc][r];
                float dist = d2 > 0.f ? __builtin_amdgcn_sqrtf(d2) : 0.f;
                pj = fmaf(a4[tr][r], dist, pj);
            }
        pj += __shfl_xor(pj, 16, 64);
        pj += __shfl_xor(pj, 32, 64);
        if (q == 0) sm.s_cpart[wr][colg] = pj;
    }
    __syncthreads();

    if (w == 0) {
        int j = lane;
        float c = sm.s_cpart[0][j] + sm.s_cpart[1][j];
        float aj = sm.s_a[j];
        bool valid = aj > 0.f;
        float cv = valid ? c : 3.4e38f;
        float mn = cv;
#pragma unroll
        for (int d = 1; d < 64; d <<= 1) mn = fminf(mn, __shfl_xor(mn, d, 64));
        float e = valid ? __expf(mn - c) * aj : 0.f;
        float s = e;
#pragma unroll
        for (int d = 1; d < 64; d <<= 1) s += __shfl_xor(s, d, 64);
        sm.s_u[j] = e * (sm.s_rsum / s);
    }
    __syncthreads();

    const int oct = t & 31, jb = t >> 5;
    float accd[8] = {0.f, 0.f, 0.f, 0.f, 0.f, 0.f, 0.f, 0.f};
#pragma unroll
    for (int jj = 0; jj < 8; ++jj) {
        int j = jb * 8 + jj;
        float u = sm.s_u[j];
        half8 xv;
        if (oct < 16) xv = *(const half8*)(Xhi + ((size_t)sm.s_cols[j] << 8) + oct * 8);
        else          xv = *(const half8*)&sm.sh[j][(oct - 16) * 8];
#pragma unroll
        for (int e = 0; e < 8; ++e) accd[e] = fmaf(u, (float)xv[e], accd[e]);
    }
#pragma unroll
    for (int e = 0; e < 8; ++e) accd[e] += __shfl_xor(accd[e], 32, 64);
    if (lane < 32) {
#pragma unroll
        for (int e = 0; e < 8; ++e) sm.s_red[w][9 * oct + e] = accd[e];
    }
    __syncthreads();
    const int idx = 9 * (t >> 3) + (t & 7);
    float o = sm.s_red[0][idx] + sm.s_red[1][idx] + sm.s_red[2][idx] + sm.s_red[3][idx];
    float res = fmaxf(o + bias[t], 0.f);
    size_t oi = (size_t)node * NHID + t;
    if (writeH) OutHi[oi] = (_Float16)res;
    else        OutF[oi] = res;
}

// ================================================================ D1: prep (xh, w1T, w2T) ∥ edge scatter
#define PREPB 512
__global__ __launch_bounds__(256) void k_prep_scatter(
    const float* __restrict__ x, _Float16* __restrict__ xh,
    const float* __restrict__ W1, _Float16* __restrict__ w1T,
    const float* __restrict__ W2, _Float16* __restrict__ w2T,
    const void* edges, int* rowcnt, int* nbr, int* deg, int E) {
    const int t = threadIdx.x;
    if ((int)blockIdx.x < PREPB) {
        const int gid = blockIdx.x * 256 + t, nthr = PREPB * 256;
        for (int i = gid; i < NNODE * 512 / 4; i += nthr) {
            float4 v = ((const float4*)x)[i];
            half4 h;
            h[0] = (_Float16)v.x; h[1] = (_Float16)v.y;
            h[2] = (_Float16)v.z; h[3] = (_Float16)v.w;
            *(half4*)&xh[4 * (size_t)i] = h;
        }
        for (int i = gid; i < 512 * NHID; i += nthr) {
            int k = i >> 8, n = i & 255;
            w1T[(size_t)n * 512 + k] = (_Float16)W1[i];
        }
        for (int i = gid; i < NHID * NHID; i += nthr) {
            int k = i >> 8, n = i & 255;
            w2T[(size_t)n * 256 + k] = (_Float16)W2[i];
        }
    } else {
        __shared__ int sflag;
        if (t < 64) {   // per-block dtype probe (L2-hot)
            const long long* e = (const long long*)edges;
            long long v = e[t];
            unsigned long long bad = __ballot(v < 0 || v >= (long long)NNODE);
            if (t == 0) sflag = (bad == 0) ? 1 : 0;
        }
        __syncthreads();
        const int fl = sflag;
        int i = ((int)blockIdx.x - PREPB) * 256 + t;
        if (i >= E + NNODE) return;
        int r, c;
        if (i < E) {
            if (fl) {
                const long long* e = (const long long*)edges;
                r = (int)e[i]; c = (int)e[E + i];
            } else {
                const int* e = (const int*)edges;
                r = e[i]; c = e[E + i];
            }
        } else { r = i - E; c = r; }   // self loop
        int pos = atomicAdd(&rowcnt[r], 1);
        if (pos < RCAP) nbr[r * RCAP + pos] = c;
        atomicAdd(&deg[c], 1);
    }
}

// ================================================================ D2: gemm1 (blocks 0..511) ∥ dedup
__global__ __launch_bounds__(256) void k_gemm1_dedup(
    const _Float16* __restrict__ xh, const _Float16* __restrict__ w1T,
    _Float16* __restrict__ X1,
    const int* __restrict__ nbr, const int* __restrict__ rowcnt,
    const int* __restrict__ deg,
    int* __restrict__ cols, float* __restrict__ wA, float* __restrict__ rsum) {
    __shared__ __align__(16) char smem[sizeof(SmemGemm)];
    if ((int)blockIdx.x < 512) {
        int g = blockIdx.x;
        gemm_body(smem, xh, w1T, X1, 512, (g >> 2) * 64, (g & 3) * 64);
    } else {
        dedup_body(smem, nbr, rowcnt, deg, cols, wA, rsum, (int)blockIdx.x - 512);
    }
}

// ================================================================ D3/D5: medoid layers
__global__ __launch_bounds__(256, 6) void k_medoid(
    const _Float16* __restrict__ X, const float* __restrict__ bias,
    float* __restrict__ OutF, _Float16* __restrict__ OutHi,
    const int* __restrict__ cols, const float* __restrict__ wts,
    const float* __restrict__ rsum, int writeH) {
    __shared__ __align__(16) SmemMedoid sm;
    const int node = blockIdx.x, t = threadIdx.x;
    if (t < 64) { sm.s_cols[t] = cols[node * KCAP + t]; sm.s_a[t] = wts[node * KCAP + t]; }
    if (t == 0) sm.s_rsum = rsum[node];
    __syncthreads();
    medoid_core(sm, X, bias, OutF, OutHi, node, writeH);
}

// ================================================================ D4: gemm layer 2
__global__ __launch_bounds__(256) void k_gemm2(
    const _Float16* __restrict__ Hh, const _Float16* __restrict__ w2T,
    _Float16* __restrict__ X2) {
    __shared__ __align__(16) char smem[sizeof(SmemGemm)];
    gemm_body(smem, Hh, w2T, X2, 256, blockIdx.x * 64, blockIdx.y * 64);
}

// ================================================================ launch
extern "C" void kernel_launch(void* const* d_in, const int* in_sizes, int n_in,
                              void* d_out, int out_size, void* d_ws, size_t ws_size,
                              hipStream_t stream) {
    const float* x  = (const float*)d_in[0];
    const void*  ei = d_in[1];
    const float* W1 = (const float*)d_in[2];
    const float* b1 = (const float*)d_in[3];
    const float* W2 = (const float*)d_in[4];
    const float* b2 = (const float*)d_in[5];
    float* out = (float*)d_out;
    const int E = in_sizes[1] / 2;

    char* p = (char*)d_ws;
    auto alloc = [&](size_t bytes) { char* q = p; p += (bytes + 255) & ~(size_t)255; return q; };
    int*      cnt    = (int*)alloc((size_t)2 * NNODE * 4);   // deg | rowcnt (single memset)
    int*      deg    = cnt;
    int*      rowcnt = cnt + NNODE;
    int*      colsA  = (int*)alloc((size_t)NNODE * KCAP * 4);
    float*    wAr    = (float*)alloc((size_t)NNODE * KCAP * 4);
    float*    rsum   = (float*)alloc((size_t)NNODE * 4);
    _Float16* xh     = (_Float16*)alloc((size_t)NNODE * 512 * 2);
    _Float16* w1T    = (_Float16*)alloc((size_t)512 * NHID * 2);
    _Float16* w2T    = (_Float16*)alloc((size_t)NHID * NHID * 2);
    _Float16* X1     = (_Float16*)alloc((size_t)NNODE * NHID * 2);   // also X2
    _Float16* Hh     = (_Float16*)alloc((size_t)NNODE * NHID * 2);
    int*      nbr    = (int*)alloc((size_t)NNODE * RCAP * 4);

    const int nscat = (E + NNODE + 255) / 256;

    hipMemsetAsync(cnt, 0, (size_t)2 * NNODE * 4, stream);
    k_prep_scatter<<<PREPB + nscat, 256, 0, stream>>>(x, xh, W1, w1T, W2, w2T,
                                                      ei, rowcnt, nbr, deg, E);
    k_gemm1_dedup<<<512 + NNODE / 2, 256, 0, stream>>>(xh, w1T, X1, nbr, rowcnt, deg,
                                                       colsA, wAr, rsum);
    k_medoid<<<NNODE, 256, 0, stream>>>(X1, b1, nullptr, Hh, colsA, wAr, rsum, 1);
    k_gemm2<<<dim3(NNODE / 64, NHID / 64), 256, 0, stream>>>(Hh, w2T, X1);
    k_medoid<<<NNODE, 256, 0, stream>>>(X1, b2, out, nullptr, colsA, wAr, rsum, 0);
}